// Round 1
// baseline (24019.495 us; speedup 1.0000x reference)
//
#include <hip/hip_runtime.h>

typedef _Float16 f16;
typedef _Float16 half8 __attribute__((ext_vector_type(8)));
typedef _Float16 half4v __attribute__((ext_vector_type(4)));
typedef float float4v __attribute__((ext_vector_type(4)));

constexpr int NB = 32;            // batch
constexpr int NT = 1024;          // time
constexpr int NH = 512;           // hidden
constexpr int NH3 = 1536;
constexpr int NM = NB * NT;       // 32768 rows

// ---------------- init: zero h ping-pong buffers + sync counters ----------------
__global__ void init_buf(f16* __restrict__ h16, unsigned* __restrict__ sync) {
    int i = blockIdx.x * 256 + threadIdx.x;
    if (i < 2 * 2 * 2 * NB * NH)   // [layer][dir][buf][NB][NH]
        h16[i] = (f16)0.f;
    if (i < 256) sync[i] = 0u;
}

// ---------------- fp32 -> fp16 convert ----------------
__global__ void cvt_f16(const float* __restrict__ src, f16* __restrict__ dst, int n4) {
    int i = blockIdx.x * blockDim.x + threadIdx.x;
    int stride = gridDim.x * blockDim.x;
    for (; i < n4; i += stride) {
        float4v v = *(const float4v*)(src + 4 * (size_t)i);
        half4v h;
        h[0] = (f16)v[0]; h[1] = (f16)v[1]; h[2] = (f16)v[2]; h[3] = (f16)v[3];
        *(half4v*)(dst + 4 * (size_t)i) = h;
    }
}

// ---------------- gi GEMM: gi[dir][m][n] = A[m][:] . W[n][:] + bias[n] ----------------
// A: [NM][K] fp16 row-major, Wf/Wr: [1536][K] fp16 row-major. N-grid covers 3072 (2 dirs).
__global__ __launch_bounds__(256, 2) void gemm_gi(
    const f16* __restrict__ A, const f16* __restrict__ Wf, const f16* __restrict__ Wr,
    const float* __restrict__ bf, const float* __restrict__ br,
    f16* __restrict__ gi, int K)
{
    __shared__ f16 As[128 * 72];
    __shared__ f16 Bs[128 * 72];
    const int m0 = blockIdx.x * 128;
    const int n0g = blockIdx.y * 128;
    const int dir = (n0g >= NH3) ? 1 : 0;
    const f16* __restrict__ W = dir ? Wr : Wf;
    const float* __restrict__ bias = dir ? br : bf;
    const int n0 = n0g - dir * NH3;
    const int tid = threadIdx.x;
    const int lane = tid & 63;
    const int wv = tid >> 6;
    const int wm = wv & 1;
    const int wn = wv >> 1;
    const int srow = tid >> 3;          // 0..31
    const int scol = (tid & 7) * 8;     // halves

    float4v acc[4][4] = {};
    for (int kb = 0; kb < K; kb += 64) {
        int4 av[4], bv[4];
#pragma unroll
        for (int i = 0; i < 4; i++) {
            av[i] = *(const int4*)(A + (size_t)(m0 + srow + i * 32) * K + kb + scol);
            bv[i] = *(const int4*)(W + (size_t)(n0 + srow + i * 32) * K + kb + scol);
        }
        __syncthreads();
#pragma unroll
        for (int i = 0; i < 4; i++) {
            *(int4*)(As + (srow + i * 32) * 72 + scol) = av[i];
            *(int4*)(Bs + (srow + i * 32) * 72 + scol) = bv[i];
        }
        __syncthreads();
#pragma unroll
        for (int ks = 0; ks < 2; ks++) {
            half8 af[4], bw[4];
#pragma unroll
            for (int i = 0; i < 4; i++) {
                af[i] = *(const half8*)(As + (wm * 64 + i * 16 + (lane & 15)) * 72 + ks * 32 + (lane >> 4) * 8);
                bw[i] = *(const half8*)(Bs + (wn * 64 + i * 16 + (lane & 15)) * 72 + ks * 32 + (lane >> 4) * 8);
            }
#pragma unroll
            for (int i = 0; i < 4; i++)
#pragma unroll
                for (int j = 0; j < 4; j++)
                    acc[i][j] = __builtin_amdgcn_mfma_f32_16x16x32_f16(af[i], bw[j], acc[i][j], 0, 0, 0);
        }
    }
    f16* __restrict__ gid = gi + (size_t)dir * NM * NH3;
#pragma unroll
    for (int i = 0; i < 4; i++) {
        const int m = m0 + wm * 64 + i * 16 + ((lane >> 4) << 2);
#pragma unroll
        for (int j = 0; j < 4; j++) {
            const int n = n0 + wn * 64 + j * 16 + (lane & 15);
            const float b = bias[n];
#pragma unroll
            for (int r = 0; r < 4; r++)
                gid[(size_t)(m + r) * NH3 + n] = (f16)(acc[i][j][r] + b);
        }
    }
}

// ---------------- GRU scan ----------------
// grid = 64 blocks: blockIdx/32 = dir, blockIdx%32 = 16-col slice. 128 threads (2 waves).
// Wave w handles batches [w*16, w*16+16). Weights (48 rows x 512) hoisted to VGPRs.
__global__ __launch_bounds__(128, 1) void gru_scan(
    const f16* __restrict__ gi,      // [2][NM][1536]
    const f16* __restrict__ Whf, const f16* __restrict__ Whr,   // [1536][512]
    const float* __restrict__ bhf, const float* __restrict__ bhr,
    f16* __restrict__ h16,           // this layer: [2 dir][2 buf][NB][NH]
    f16* __restrict__ y16,           // layer0 output (fp16) or nullptr
    float* __restrict__ y32,         // layer1 output (fp32, d_out) or nullptr
    float* __restrict__ hlast,       // [2][NB][NH] fp32
    unsigned* __restrict__ sync)     // counters at sync[d*32]
{
    __shared__ f16 Wlds[48 * 520];
    const int d = blockIdx.x >> 5;
    const int cs = blockIdx.x & 31;
    const int c0 = cs * 16;
    const f16* __restrict__ W = d ? Whr : Whf;
    const float* __restrict__ bhh = d ? bhr : bhf;
    const int tid = threadIdx.x;
    const int lane = tid & 63;
    const int mt = tid >> 6;         // wave index = batch half

    // stage W_hh rows {g*512 + c0 + j} into LDS (row-major [48][520], padded)
    for (int c = tid; c < 48 * 64; c += 128) {
        const int row = c >> 6;
        const int off = (c & 63) * 8;
        const int g = row >> 4, j = row & 15;
        *(int4*)(Wlds + row * 520 + off) = *(const int4*)(W + (size_t)(g * 512 + c0 + j) * 512 + off);
    }
    const int cl = c0 + (lane & 15);
    float bh[3];
#pragma unroll
    for (int g = 0; g < 3; g++) bh[g] = bhh[g * 512 + cl];
    __syncthreads();

    // hoist B fragments (step-invariant) into registers: 48 x half8
    half8 bfr[16][3];
#pragma unroll
    for (int kk = 0; kk < 16; kk++)
#pragma unroll
        for (int g = 0; g < 3; g++)
            bfr[kk][g] = *(const half8*)(Wlds + (g * 16 + (lane & 15)) * 520 + kk * 32 + (lane >> 4) * 8);

    const f16* __restrict__ giD = gi + (size_t)d * NM * NH3;
    f16* const h16D = h16 + d * (2 * NB * NH);
    unsigned* const ctr = sync + d * 32;
    const int bA = mt * 16 + (lane & 15);          // A-frag row (batch)
    const int bC = mt * 16 + ((lane >> 4) << 2);   // C-frag batch base (+r)
    float h32[4] = {0.f, 0.f, 0.f, 0.f};
    float gif[3][4];
    {
        const int te = d ? (NT - 1) : 0;
#pragma unroll
        for (int r = 0; r < 4; r++) {
            const f16* p = giD + ((size_t)(bC + r) * NT + te) * NH3;
#pragma unroll
            for (int g = 0; g < 3; g++) gif[g][r] = (float)p[g * 512 + cl];
        }
    }

    for (int t = 0; t < NT; t++) {
        const int te = d ? (NT - 1 - t) : t;
        const f16* const hrd = h16D + (t & 1) * (NB * NH);
        f16* const hwr = h16D + ((t + 1) & 1) * (NB * NH);

        // A fragments: h[bA][k] fp16
        half8 afr[16];
        {
            const f16* hp = hrd + bA * NH + (lane >> 4) * 8;
#pragma unroll
            for (int kk = 0; kk < 16; kk++)
                afr[kk] = *(const half8*)(hp + kk * 32);
        }
        float4v acc[3] = {};
#pragma unroll
        for (int kk = 0; kk < 16; kk++)
#pragma unroll
            for (int g = 0; g < 3; g++)
                acc[g] = __builtin_amdgcn_mfma_f32_16x16x32_f16(afr[kk], bfr[kk][g], acc[g], 0, 0, 0);

        float hnew[4]; f16 hnew16[4];
#pragma unroll
        for (int r = 0; r < 4; r++) {
            const float hr = acc[0][r] + bh[0];
            const float hz = acc[1][r] + bh[1];
            const float hn = acc[2][r] + bh[2];
            const float rg = 1.f / (1.f + __expf(-(gif[0][r] + hr)));
            const float zg = 1.f / (1.f + __expf(-(gif[1][r] + hz)));
            const float x2 = gif[2][r] + rg * hn;
            const float e2 = __expf(x2 + x2);
            const float ng = 1.f - 2.f / (e2 + 1.f);
            const float h = (1.f - zg) * ng + zg * h32[r];
            h32[r] = h; hnew[r] = h; hnew16[r] = (f16)h;
        }
        // publish h for next step (ping-pong buffer)
#pragma unroll
        for (int r = 0; r < 4; r++)
            hwr[(bC + r) * NH + cl] = hnew16[r];

        const bool more = (t + 1 < NT);
        if (more) {
            __threadfence();
            __syncthreads();
            if (tid == 0)
                __hip_atomic_fetch_add(ctr, 1u, __ATOMIC_RELEASE, __HIP_MEMORY_SCOPE_AGENT);
        }
        // y output (overlaps the spin)
#pragma unroll
        for (int r = 0; r < 4; r++) {
            const size_t yoff = ((size_t)(bC + r) * NT + te) * (2 * NH) + d * NH + cl;
            if (y16) y16[yoff] = hnew16[r];
            else     y32[yoff] = hnew[r];
        }
        if (t == NT - 1) {
#pragma unroll
            for (int r = 0; r < 4; r++)
                hlast[d * NB * NH + (bC + r) * NH + cl] = hnew[r];
        }
        if (more) {
            // prefetch gi for t+1 while spinning
            const int te2 = d ? (NT - 2 - t) : (t + 1);
#pragma unroll
            for (int r = 0; r < 4; r++) {
                const f16* p = giD + ((size_t)(bC + r) * NT + te2) * NH3;
#pragma unroll
                for (int g = 0; g < 3; g++) gif[g][r] = (float)p[g * 512 + cl];
            }
            if (tid == 0) {
                const unsigned target = 32u * (unsigned)(t + 1);
                while (__hip_atomic_load(ctr, __ATOMIC_RELAXED, __HIP_MEMORY_SCOPE_AGENT) < target)
                    __builtin_amdgcn_s_sleep(1);
                __threadfence();   // acquire: make all peers' h stores visible
            }
            __syncthreads();
        }
    }
}

extern "C" void kernel_launch(void* const* d_in, const int* in_sizes, int n_in,
                              void* d_out, int out_size, void* d_ws, size_t ws_size,
                              hipStream_t stream) {
    (void)in_sizes; (void)n_in; (void)out_size; (void)ws_size;
    const float* X     = (const float*)d_in[0];
    const float* wih0f = (const float*)d_in[1];
    const float* bih0f = (const float*)d_in[2];
    const float* whh0f = (const float*)d_in[3];
    const float* bhh0f = (const float*)d_in[4];
    const float* wih0r = (const float*)d_in[5];
    const float* bih0r = (const float*)d_in[6];
    const float* whh0r = (const float*)d_in[7];
    const float* bhh0r = (const float*)d_in[8];
    const float* wih1f = (const float*)d_in[9];
    const float* bih1f = (const float*)d_in[10];
    const float* whh1f = (const float*)d_in[11];
    const float* bhh1f = (const float*)d_in[12];
    const float* wih1r = (const float*)d_in[13];
    const float* bih1r = (const float*)d_in[14];
    const float* whh1r = (const float*)d_in[15];
    const float* bhh1r = (const float*)d_in[16];

    char* ws = (char*)d_ws;
    f16* Xh   = (f16*)(ws + 0ull);
    f16* Wi0f = (f16*)(ws + 33554432ull);
    f16* Wi0r = (f16*)(ws + 35127296ull);
    f16* Wh0f = (f16*)(ws + 36700160ull);
    f16* Wh0r = (f16*)(ws + 38273024ull);
    f16* Wi1f = (f16*)(ws + 39845888ull);
    f16* Wi1r = (f16*)(ws + 42991616ull);
    f16* Wh1f = (f16*)(ws + 46137344ull);
    f16* Wh1r = (f16*)(ws + 47710208ull);
    f16* Y0h  = (f16*)(ws + 49283072ull);
    f16* H16  = (f16*)(ws + 116391936ull);
    unsigned* SYNC = (unsigned*)(ws + 116654080ull);
    f16* GI   = (f16*)(ws + 116655104ull);
    float* out = (float*)d_out;

    init_buf<<<512, 256, 0, stream>>>(H16, SYNC);

    auto cvt = [&](const float* s, f16* d, size_t n) {
        int n4 = (int)(n / 4);
        int grid = (n4 + 255) / 256; if (grid > 4096) grid = 4096;
        cvt_f16<<<grid, 256, 0, stream>>>(s, d, n4);
    };
    cvt(X,     Xh,   (size_t)NM * NH);
    cvt(wih0f, Wi0f, (size_t)NH3 * NH);
    cvt(wih0r, Wi0r, (size_t)NH3 * NH);
    cvt(whh0f, Wh0f, (size_t)NH3 * NH);
    cvt(whh0r, Wh0r, (size_t)NH3 * NH);
    cvt(wih1f, Wi1f, (size_t)NH3 * 2 * NH);
    cvt(wih1r, Wi1r, (size_t)NH3 * 2 * NH);
    cvt(whh1f, Wh1f, (size_t)NH3 * NH);
    cvt(whh1r, Wh1r, (size_t)NH3 * NH);

    const size_t OUT0 = (size_t)NM * 2 * NH;   // 33,554,432 floats

    // Layer 0
    gemm_gi<<<dim3(NM / 128, 24), 256, 0, stream>>>(Xh, Wi0f, Wi0r, bih0f, bih0r, GI, NH);
    gru_scan<<<64, 128, 0, stream>>>(GI, Wh0f, Wh0r, bhh0f, bhh0r,
                                     H16, Y0h, nullptr,
                                     out + OUT0, SYNC);
    // Layer 1
    gemm_gi<<<dim3(NM / 128, 24), 256, 0, stream>>>(Y0h, Wi1f, Wi1r, bih1f, bih1r, GI, 2 * NH);
    gru_scan<<<64, 128, 0, stream>>>(GI, Wh1f, Wh1r, bhh1f, bhh1r,
                                     H16 + 2 * 2 * NB * NH, nullptr, out,
                                     out + OUT0 + 2 * NB * NH, SYNC + 64);
}

// Round 2
// 11301.834 us; speedup vs baseline: 2.1253x; 2.1253x over previous
//
#include <hip/hip_runtime.h>

typedef _Float16 f16;
typedef _Float16 half8 __attribute__((ext_vector_type(8)));
typedef _Float16 half4v __attribute__((ext_vector_type(4)));
typedef float float4v __attribute__((ext_vector_type(4)));

constexpr int NB = 32;            // batch
constexpr int NT = 1024;          // time
constexpr int NH = 512;           // hidden
constexpr int NH3 = 1536;
constexpr int NM = NB * NT;       // 32768 rows

// ---------------- init: zero h ping-pong buffers + sync counters ----------------
__global__ void init_buf(f16* __restrict__ h16, unsigned* __restrict__ sync) {
    int i = blockIdx.x * 256 + threadIdx.x;
    if (i < 2 * 2 * 2 * NB * NH)   // [layer][dir][buf][NB][NH]
        h16[i] = (f16)0.f;
    if (i < 256) sync[i] = 0u;
}

// ---------------- fp32 -> fp16 convert ----------------
__global__ void cvt_f16(const float* __restrict__ src, f16* __restrict__ dst, int n4) {
    int i = blockIdx.x * blockDim.x + threadIdx.x;
    int stride = gridDim.x * blockDim.x;
    for (; i < n4; i += stride) {
        float4v v = *(const float4v*)(src + 4 * (size_t)i);
        half4v h;
        h[0] = (f16)v[0]; h[1] = (f16)v[1]; h[2] = (f16)v[2]; h[3] = (f16)v[3];
        *(half4v*)(dst + 4 * (size_t)i) = h;
    }
}

// ---------------- gi GEMM: gi[dir][m][n] = A[m][:] . W[n][:] + bias[n] ----------------
__global__ __launch_bounds__(256, 2) void gemm_gi(
    const f16* __restrict__ A, const f16* __restrict__ Wf, const f16* __restrict__ Wr,
    const float* __restrict__ bf, const float* __restrict__ br,
    f16* __restrict__ gi, int K)
{
    __shared__ f16 As[128 * 72];
    __shared__ f16 Bs[128 * 72];
    const int m0 = blockIdx.x * 128;
    const int n0g = blockIdx.y * 128;
    const int dir = (n0g >= NH3) ? 1 : 0;
    const f16* __restrict__ W = dir ? Wr : Wf;
    const float* __restrict__ bias = dir ? br : bf;
    const int n0 = n0g - dir * NH3;
    const int tid = threadIdx.x;
    const int lane = tid & 63;
    const int wv = tid >> 6;
    const int wm = wv & 1;
    const int wn = wv >> 1;
    const int srow = tid >> 3;          // 0..31
    const int scol = (tid & 7) * 8;     // halves

    float4v acc[4][4] = {};
    for (int kb = 0; kb < K; kb += 64) {
        int4 av[4], bv[4];
#pragma unroll
        for (int i = 0; i < 4; i++) {
            av[i] = *(const int4*)(A + (size_t)(m0 + srow + i * 32) * K + kb + scol);
            bv[i] = *(const int4*)(W + (size_t)(n0 + srow + i * 32) * K + kb + scol);
        }
        __syncthreads();
#pragma unroll
        for (int i = 0; i < 4; i++) {
            *(int4*)(As + (srow + i * 32) * 72 + scol) = av[i];
            *(int4*)(Bs + (srow + i * 32) * 72 + scol) = bv[i];
        }
        __syncthreads();
#pragma unroll
        for (int ks = 0; ks < 2; ks++) {
            half8 af[4], bw[4];
#pragma unroll
            for (int i = 0; i < 4; i++) {
                af[i] = *(const half8*)(As + (wm * 64 + i * 16 + (lane & 15)) * 72 + ks * 32 + (lane >> 4) * 8);
                bw[i] = *(const half8*)(Bs + (wn * 64 + i * 16 + (lane & 15)) * 72 + ks * 32 + (lane >> 4) * 8);
            }
#pragma unroll
            for (int i = 0; i < 4; i++)
#pragma unroll
                for (int j = 0; j < 4; j++)
                    acc[i][j] = __builtin_amdgcn_mfma_f32_16x16x32_f16(af[i], bw[j], acc[i][j], 0, 0, 0);
        }
    }
    f16* __restrict__ gid = gi + (size_t)dir * NM * NH3;
#pragma unroll
    for (int i = 0; i < 4; i++) {
        const int m = m0 + wm * 64 + i * 16 + ((lane >> 4) << 2);
#pragma unroll
        for (int j = 0; j < 4; j++) {
            const int n = n0 + wn * 64 + j * 16 + (lane & 15);
            const float b = bias[n];
#pragma unroll
            for (int r = 0; r < 4; r++)
                gid[(size_t)(m + r) * NH3 + n] = (f16)(acc[i][j][r] + b);
        }
    }
}

// ---------------- device-coherent (L1/L2-bypassing) helpers ----------------
__device__ __forceinline__ unsigned long long ld_dev_u64(const void* p) {
    return __hip_atomic_load((const unsigned long long*)p,
                             __ATOMIC_RELAXED, __HIP_MEMORY_SCOPE_AGENT);
}
__device__ __forceinline__ void st_dev_u16(void* p, unsigned short v) {
    __hip_atomic_store((unsigned short*)p, v,
                       __ATOMIC_RELAXED, __HIP_MEMORY_SCOPE_AGENT);
}

union U8x2 { unsigned long long u[2]; half8 h; };

// ---------------- GRU scan ----------------
// grid = 64 blocks: blockIdx/32 = dir, blockIdx%32 = 16-col slice. 128 threads (2 waves).
// h exchange goes through the coherence point (relaxed agent-scope atomics, sc0/sc1
// cache-bypass) -> NO per-step agent fences (buffer_wbl2/inv), which dominated round 1.
__global__ __launch_bounds__(128, 1) void gru_scan(
    const f16* __restrict__ gi,      // [2][NM][1536]
    const f16* __restrict__ Whf, const f16* __restrict__ Whr,   // [1536][512]
    const float* __restrict__ bhf, const float* __restrict__ bhr,
    f16* __restrict__ h16,           // this layer: [2 dir][2 buf][NB][NH]
    f16* __restrict__ y16,           // layer0 output (fp16) or nullptr
    float* __restrict__ y32,         // layer1 output (fp32, d_out) or nullptr
    float* __restrict__ hlast,       // [2][NB][NH] fp32
    unsigned* __restrict__ sync)     // counters at sync[d*32]
{
    __shared__ f16 Wlds[48 * 520];
    const int d = blockIdx.x >> 5;
    const int cs = blockIdx.x & 31;
    const int c0 = cs * 16;
    const f16* __restrict__ W = d ? Whr : Whf;
    const float* __restrict__ bhh = d ? bhr : bhf;
    const int tid = threadIdx.x;
    const int lane = tid & 63;
    const int mt = tid >> 6;         // wave index = batch half

    // stage W_hh rows {g*512 + c0 + j} into LDS (row-major [48][520], padded)
    for (int c = tid; c < 48 * 64; c += 128) {
        const int row = c >> 6;
        const int off = (c & 63) * 8;
        const int g = row >> 4, j = row & 15;
        *(int4*)(Wlds + row * 520 + off) = *(const int4*)(W + (size_t)(g * 512 + c0 + j) * 512 + off);
    }
    const int cl = c0 + (lane & 15);
    float bh[3];
#pragma unroll
    for (int g = 0; g < 3; g++) bh[g] = bhh[g * 512 + cl];
    __syncthreads();

    // hoist B fragments (step-invariant) into registers: 48 x half8
    half8 bfr[16][3];
#pragma unroll
    for (int kk = 0; kk < 16; kk++)
#pragma unroll
        for (int g = 0; g < 3; g++)
            bfr[kk][g] = *(const half8*)(Wlds + (g * 16 + (lane & 15)) * 520 + kk * 32 + (lane >> 4) * 8);

    const f16* __restrict__ giD = gi + (size_t)d * NM * NH3;
    f16* const h16D = h16 + d * (2 * NB * NH);
    unsigned* const ctr = sync + d * 32;
    const int bA = mt * 16 + (lane & 15);          // A-frag row (batch)
    const int bC = mt * 16 + ((lane >> 4) << 2);   // C-frag batch base (+r)
    float h32[4] = {0.f, 0.f, 0.f, 0.f};
    float gif[3][4];
    {
        const int te = d ? (NT - 1) : 0;
#pragma unroll
        for (int r = 0; r < 4; r++) {
            const f16* p = giD + ((size_t)(bC + r) * NT + te) * NH3;
#pragma unroll
            for (int g = 0; g < 3; g++) gif[g][r] = (float)p[g * 512 + cl];
        }
    }

    for (int t = 0; t < NT; t++) {
        const int te = d ? (NT - 1 - t) : t;
        const f16* const hrd = h16D + (t & 1) * (NB * NH);
        f16* const hwr = h16D + ((t + 1) & 1) * (NB * NH);

        // A fragments: h[bA][k] fp16 via coherence-point loads (no cache staleness)
        half8 afr[16];
        {
            const f16* hp = hrd + bA * NH + (lane >> 4) * 8;
#pragma unroll
            for (int kk = 0; kk < 16; kk++) {
                U8x2 u;
                u.u[0] = ld_dev_u64(hp + kk * 32);
                u.u[1] = ld_dev_u64(hp + kk * 32 + 4);
                afr[kk] = u.h;
            }
        }
        float4v acc[3] = {};
#pragma unroll
        for (int kk = 0; kk < 16; kk++)
#pragma unroll
            for (int g = 0; g < 3; g++)
                acc[g] = __builtin_amdgcn_mfma_f32_16x16x32_f16(afr[kk], bfr[kk][g], acc[g], 0, 0, 0);

        float hnew[4]; f16 hnew16[4];
#pragma unroll
        for (int r = 0; r < 4; r++) {
            const float hr = acc[0][r] + bh[0];
            const float hz = acc[1][r] + bh[1];
            const float hn = acc[2][r] + bh[2];
            const float rg = 1.f / (1.f + __expf(-(gif[0][r] + hr)));
            const float zg = 1.f / (1.f + __expf(-(gif[1][r] + hz)));
            const float x2 = gif[2][r] + rg * hn;
            const float e2 = __expf(x2 + x2);
            const float ng = 1.f - 2.f / (e2 + 1.f);
            const float h = (1.f - zg) * ng + zg * h32[r];
            h32[r] = h; hnew[r] = h; hnew16[r] = (f16)h;
        }
        // publish h for next step (coherence-point stores, ping-pong buffer)
#pragma unroll
        for (int r = 0; r < 4; r++)
            st_dev_u16(&hwr[(bC + r) * NH + cl],
                       __builtin_bit_cast(unsigned short, hnew16[r]));

        const bool more = (t + 1 < NT);
        if (more) {
            // __syncthreads drains each wave's vmcnt (loads AND stores) before the
            // barrier -> tid0's counter add below is only issued after every h store
            // (and every h read of this step, for ping-pong WAR safety) completed.
            __syncthreads();
            if (tid == 0)
                __hip_atomic_fetch_add(ctr, 1u, __ATOMIC_RELAXED, __HIP_MEMORY_SCOPE_AGENT);
        }
        // y output (plain cached stores; consumer is a later kernel -> runtime coherence)
#pragma unroll
        for (int r = 0; r < 4; r++) {
            const size_t yoff = ((size_t)(bC + r) * NT + te) * (2 * NH) + d * NH + cl;
            if (y16) y16[yoff] = hnew16[r];
            else     y32[yoff] = hnew[r];
        }
        if (t == NT - 1) {
#pragma unroll
            for (int r = 0; r < 4; r++)
                hlast[d * NB * NH + (bC + r) * NH + cl] = hnew[r];
        }
        if (more) {
            // prefetch gi for t+1 while spinning (plain cached loads, in flight)
            const int te2 = d ? (NT - 2 - t) : (t + 1);
#pragma unroll
            for (int r = 0; r < 4; r++) {
                const f16* p = giD + ((size_t)(bC + r) * NT + te2) * NH3;
#pragma unroll
                for (int g = 0; g < 3; g++) gif[g][r] = (float)p[g * 512 + cl];
            }
            if (tid == 0) {
                const unsigned target = 32u * (unsigned)(t + 1);
                while (__hip_atomic_load(ctr, __ATOMIC_RELAXED, __HIP_MEMORY_SCOPE_AGENT) < target)
                    __builtin_amdgcn_s_sleep(1);
                // one acquire load at exit (cheap) to pin the ordering story
                (void)__hip_atomic_load(ctr, __ATOMIC_ACQUIRE, __HIP_MEMORY_SCOPE_AGENT);
            }
            __syncthreads();
        }
    }
}

extern "C" void kernel_launch(void* const* d_in, const int* in_sizes, int n_in,
                              void* d_out, int out_size, void* d_ws, size_t ws_size,
                              hipStream_t stream) {
    (void)in_sizes; (void)n_in; (void)out_size; (void)ws_size;
    const float* X     = (const float*)d_in[0];
    const float* wih0f = (const float*)d_in[1];
    const float* bih0f = (const float*)d_in[2];
    const float* whh0f = (const float*)d_in[3];
    const float* bhh0f = (const float*)d_in[4];
    const float* wih0r = (const float*)d_in[5];
    const float* bih0r = (const float*)d_in[6];
    const float* whh0r = (const float*)d_in[7];
    const float* bhh0r = (const float*)d_in[8];
    const float* wih1f = (const float*)d_in[9];
    const float* bih1f = (const float*)d_in[10];
    const float* whh1f = (const float*)d_in[11];
    const float* bhh1f = (const float*)d_in[12];
    const float* wih1r = (const float*)d_in[13];
    const float* bih1r = (const float*)d_in[14];
    const float* whh1r = (const float*)d_in[15];
    const float* bhh1r = (const float*)d_in[16];

    char* ws = (char*)d_ws;
    f16* Xh   = (f16*)(ws + 0ull);
    f16* Wi0f = (f16*)(ws + 33554432ull);
    f16* Wi0r = (f16*)(ws + 35127296ull);
    f16* Wh0f = (f16*)(ws + 36700160ull);
    f16* Wh0r = (f16*)(ws + 38273024ull);
    f16* Wi1f = (f16*)(ws + 39845888ull);
    f16* Wi1r = (f16*)(ws + 42991616ull);
    f16* Wh1f = (f16*)(ws + 46137344ull);
    f16* Wh1r = (f16*)(ws + 47710208ull);
    f16* Y0h  = (f16*)(ws + 49283072ull);
    f16* H16  = (f16*)(ws + 116391936ull);
    unsigned* SYNC = (unsigned*)(ws + 116654080ull);
    f16* GI   = (f16*)(ws + 116655104ull);
    float* out = (float*)d_out;

    init_buf<<<512, 256, 0, stream>>>(H16, SYNC);

    auto cvt = [&](const float* s, f16* d, size_t n) {
        int n4 = (int)(n / 4);
        int grid = (n4 + 255) / 256; if (grid > 4096) grid = 4096;
        cvt_f16<<<grid, 256, 0, stream>>>(s, d, n4);
    };
    cvt(X,     Xh,   (size_t)NM * NH);
    cvt(wih0f, Wi0f, (size_t)NH3 * NH);
    cvt(wih0r, Wi0r, (size_t)NH3 * NH);
    cvt(whh0f, Wh0f, (size_t)NH3 * NH);
    cvt(whh0r, Wh0r, (size_t)NH3 * NH);
    cvt(wih1f, Wi1f, (size_t)NH3 * 2 * NH);
    cvt(wih1r, Wi1r, (size_t)NH3 * 2 * NH);
    cvt(whh1f, Wh1f, (size_t)NH3 * NH);
    cvt(whh1r, Wh1r, (size_t)NH3 * NH);

    const size_t OUT0 = (size_t)NM * 2 * NH;   // 33,554,432 floats

    // Layer 0
    gemm_gi<<<dim3(NM / 128, 24), 256, 0, stream>>>(Xh, Wi0f, Wi0r, bih0f, bih0r, GI, NH);
    gru_scan<<<64, 128, 0, stream>>>(GI, Wh0f, Wh0r, bhh0f, bhh0r,
                                     H16, Y0h, nullptr,
                                     out + OUT0, SYNC);
    // Layer 1
    gemm_gi<<<dim3(NM / 128, 24), 256, 0, stream>>>(Y0h, Wi1f, Wi1r, bih1f, bih1r, GI, 2 * NH);
    gru_scan<<<64, 128, 0, stream>>>(GI, Wh1f, Wh1r, bhh1f, bhh1r,
                                     H16 + 2 * 2 * NB * NH, nullptr, out,
                                     out + OUT0 + 2 * NB * NH, SYNC + 64);
}

// Round 4
// 10368.116 us; speedup vs baseline: 2.3167x; 1.0901x over previous
//
#include <hip/hip_runtime.h>

typedef _Float16 f16;
typedef _Float16 half8 __attribute__((ext_vector_type(8)));
typedef _Float16 half4v __attribute__((ext_vector_type(4)));
typedef float float4v __attribute__((ext_vector_type(4)));

constexpr int NB = 32;            // batch
constexpr int NT = 1024;          // time
constexpr int NH = 512;           // hidden
constexpr int NH3 = 1536;
constexpr int NM = NB * NT;       // 32768 rows

// ---------------- init: zero h ping-pong buffers + sync flags ----------------
__global__ void init_buf(f16* __restrict__ h16, unsigned* __restrict__ sync) {
    int i = blockIdx.x * 256 + threadIdx.x;
    if (i < 2 * 2 * 2 * NB * NH)   // [layer][dir][buf][NB][NH]
        h16[i] = (f16)0.f;
    if (i < 256) sync[i] = 0u;
}

// ---------------- fp32 -> fp16 convert ----------------
__global__ void cvt_f16(const float* __restrict__ src, f16* __restrict__ dst, int n4) {
    int i = blockIdx.x * blockDim.x + threadIdx.x;
    int stride = gridDim.x * blockDim.x;
    for (; i < n4; i += stride) {
        float4v v = *(const float4v*)(src + 4 * (size_t)i);
        half4v h;
        h[0] = (f16)v[0]; h[1] = (f16)v[1]; h[2] = (f16)v[2]; h[3] = (f16)v[3];
        *(half4v*)(dst + 4 * (size_t)i) = h;
    }
}

// ---------------- gi GEMM: gi[dir][m][n] = A[m][:] . W[n][:] + bias[n] ----------------
__global__ __launch_bounds__(256, 2) void gemm_gi(
    const f16* __restrict__ A, const f16* __restrict__ Wf, const f16* __restrict__ Wr,
    const float* __restrict__ bf, const float* __restrict__ br,
    f16* __restrict__ gi, int K)
{
    __shared__ f16 As[128 * 72];
    __shared__ f16 Bs[128 * 72];
    const int m0 = blockIdx.x * 128;
    const int n0g = blockIdx.y * 128;
    const int dir = (n0g >= NH3) ? 1 : 0;
    const f16* __restrict__ W = dir ? Wr : Wf;
    const float* __restrict__ bias = dir ? br : bf;
    const int n0 = n0g - dir * NH3;
    const int tid = threadIdx.x;
    const int lane = tid & 63;
    const int wv = tid >> 6;
    const int wm = wv & 1;
    const int wn = wv >> 1;
    const int srow = tid >> 3;          // 0..31
    const int scol = (tid & 7) * 8;     // halves

    float4v acc[4][4] = {};
    for (int kb = 0; kb < K; kb += 64) {
        int4 av[4], bv[4];
#pragma unroll
        for (int i = 0; i < 4; i++) {
            av[i] = *(const int4*)(A + (size_t)(m0 + srow + i * 32) * K + kb + scol);
            bv[i] = *(const int4*)(W + (size_t)(n0 + srow + i * 32) * K + kb + scol);
        }
        __syncthreads();
#pragma unroll
        for (int i = 0; i < 4; i++) {
            *(int4*)(As + (srow + i * 32) * 72 + scol) = av[i];
            *(int4*)(Bs + (srow + i * 32) * 72 + scol) = bv[i];
        }
        __syncthreads();
#pragma unroll
        for (int ks = 0; ks < 2; ks++) {
            half8 af[4], bw[4];
#pragma unroll
            for (int i = 0; i < 4; i++) {
                af[i] = *(const half8*)(As + (wm * 64 + i * 16 + (lane & 15)) * 72 + ks * 32 + (lane >> 4) * 8);
                bw[i] = *(const half8*)(Bs + (wn * 64 + i * 16 + (lane & 15)) * 72 + ks * 32 + (lane >> 4) * 8);
            }
#pragma unroll
            for (int i = 0; i < 4; i++)
#pragma unroll
                for (int j = 0; j < 4; j++)
                    acc[i][j] = __builtin_amdgcn_mfma_f32_16x16x32_f16(af[i], bw[j], acc[i][j], 0, 0, 0);
        }
    }
    f16* __restrict__ gid = gi + (size_t)dir * NM * NH3;
#pragma unroll
    for (int i = 0; i < 4; i++) {
        const int m = m0 + wm * 64 + i * 16 + ((lane >> 4) << 2);
#pragma unroll
        for (int j = 0; j < 4; j++) {
            const int n = n0 + wn * 64 + j * 16 + (lane & 15);
            const float b = bias[n];
#pragma unroll
            for (int r = 0; r < 4; r++)
                gid[(size_t)(m + r) * NH3 + n] = (f16)(acc[i][j][r] + b);
        }
    }
}

// ---------------- device-coherent (cache-bypassing) helpers ----------------
__device__ __forceinline__ unsigned long long ld_dev_u64(const void* p) {
    return __hip_atomic_load((const unsigned long long*)p,
                             __ATOMIC_RELAXED, __HIP_MEMORY_SCOPE_AGENT);
}
__device__ __forceinline__ void st_dev_u16(void* p, unsigned short v) {
    __hip_atomic_store((unsigned short*)p, v,
                       __ATOMIC_RELAXED, __HIP_MEMORY_SCOPE_AGENT);
}
__device__ __forceinline__ void st_dev_u32(void* p, unsigned v) {
    __hip_atomic_store((unsigned*)p, v,
                       __ATOMIC_RELAXED, __HIP_MEMORY_SCOPE_AGENT);
}

union U8x2 { unsigned long long u[2]; half8 h; };

// ---------------- GRU scan ----------------
// grid = 64 blocks: blockIdx/32 = dir, blockIdx%32 = 16-col slice. 128 threads (2 waves).
// Cross-block step barrier: per-block MONOTONIC u32 step counter (no same-address RMW,
// and crucially: pollers test >= so a leader overwriting its flag with a LARGER value
// can never strand a laggard — the round-3 exact-match flags deadlocked).
// No acquire fences (no L2 invalidation): flag+data both resolve at the coherence
// point, and h-loads issue only after the poll branch resolves.
__global__ __launch_bounds__(128, 1) void gru_scan(
    const f16* __restrict__ gi,      // [2][NM][1536]
    const f16* __restrict__ Whf, const f16* __restrict__ Whr,   // [1536][512]
    const float* __restrict__ bhf, const float* __restrict__ bhr,
    f16* __restrict__ h16,           // this layer: [2 dir][2 buf][NB][NH]
    f16* __restrict__ y16,           // layer0 output (fp16) or nullptr
    float* __restrict__ y32,         // layer1 output (fp32, d_out) or nullptr
    float* __restrict__ hlast,       // [2][NB][NH] fp32
    unsigned* __restrict__ flags)    // [2 dir][32] u32, zero-initialized
{
    __shared__ f16 Wlds[48 * 520];
    const int d = blockIdx.x >> 5;
    const int cs = blockIdx.x & 31;
    const int c0 = cs * 16;
    const f16* __restrict__ W = d ? Whr : Whf;
    const float* __restrict__ bhh = d ? bhr : bhf;
    const int tid = threadIdx.x;
    const int lane = tid & 63;
    const int mt = tid >> 6;         // wave index = batch half

    unsigned* const myflag = flags + d * 32 + cs;
    const unsigned long long* const FQ = (const unsigned long long*)(flags + d * 32);

    // stage W_hh rows {g*512 + c0 + j} into LDS (row-major [48][520], padded)
    for (int c = tid; c < 48 * 64; c += 128) {
        const int row = c >> 6;
        const int off = (c & 63) * 8;
        const int g = row >> 4, j = row & 15;
        *(int4*)(Wlds + row * 520 + off) = *(const int4*)(W + (size_t)(g * 512 + c0 + j) * 512 + off);
    }
    const int cl = c0 + (lane & 15);
    float bh[3];
#pragma unroll
    for (int g = 0; g < 3; g++) bh[g] = bhh[g * 512 + cl];
    __syncthreads();

    // hoist B fragments (step-invariant) into registers: 48 x half8
    half8 bfr[16][3];
#pragma unroll
    for (int kk = 0; kk < 16; kk++)
#pragma unroll
        for (int g = 0; g < 3; g++)
            bfr[kk][g] = *(const half8*)(Wlds + (g * 16 + (lane & 15)) * 520 + kk * 32 + (lane >> 4) * 8);

    const f16* __restrict__ giD = gi + (size_t)d * NM * NH3;
    f16* const h16D = h16 + d * (2 * NB * NH);
    const int bA = mt * 16 + (lane & 15);          // A-frag row (batch)
    const int bC = mt * 16 + ((lane >> 4) << 2);   // C-frag batch base (+r)
    float h32[4] = {0.f, 0.f, 0.f, 0.f};
    float gif[3][4];
    {
        const int te = d ? (NT - 1) : 0;
#pragma unroll
        for (int r = 0; r < 4; r++) {
            const f16* p = giD + ((size_t)(bC + r) * NT + te) * NH3;
#pragma unroll
            for (int g = 0; g < 3; g++) gif[g][r] = (float)p[g * 512 + cl];
        }
    }

    for (int t = 0; t < NT; t++) {
        const int te = d ? (NT - 1 - t) : t;
        const f16* const hrd = h16D + (t & 1) * (NB * NH);
        f16* const hwr = h16D + ((t + 1) & 1) * (NB * NH);

        // A fragments: h[bA][k] fp16 via coherence-point loads
        half8 afr[16];
        {
            const f16* hp = hrd + bA * NH + (lane >> 4) * 8;
#pragma unroll
            for (int kk = 0; kk < 16; kk++) {
                U8x2 u;
                u.u[0] = ld_dev_u64(hp + kk * 32);
                u.u[1] = ld_dev_u64(hp + kk * 32 + 4);
                afr[kk] = u.h;
            }
        }
        float4v acc[3] = {};
#pragma unroll
        for (int kk = 0; kk < 16; kk++)
#pragma unroll
            for (int g = 0; g < 3; g++)
                acc[g] = __builtin_amdgcn_mfma_f32_16x16x32_f16(afr[kk], bfr[kk][g], acc[g], 0, 0, 0);

        float hnew[4]; f16 hnew16[4];
#pragma unroll
        for (int r = 0; r < 4; r++) {
            const float hr = acc[0][r] + bh[0];
            const float hz = acc[1][r] + bh[1];
            const float hn = acc[2][r] + bh[2];
            const float rg = 1.f / (1.f + __expf(-(gif[0][r] + hr)));
            const float zg = 1.f / (1.f + __expf(-(gif[1][r] + hz)));
            const float x2 = gif[2][r] + rg * hn;
            const float e2 = __expf(x2 + x2);
            const float ng = 1.f - 2.f / (e2 + 1.f);
            const float h = (1.f - zg) * ng + zg * h32[r];
            h32[r] = h; hnew[r] = h; hnew16[r] = (f16)h;
        }

        const bool more = (t + 1 < NT);
        if (more) {
            // publish h for next step (coherence-point stores, ping-pong buffer)
#pragma unroll
            for (int r = 0; r < 4; r++)
                st_dev_u16(&hwr[(bC + r) * NH + cl],
                           __builtin_bit_cast(unsigned short, hnew16[r]));
            // Drain this block's h stores AND h/gi reads (WAR safety) before the flag.
            __syncthreads();
            if (tid == 0)
                st_dev_u32(myflag, (unsigned)(t + 1));   // steps completed (monotonic)
            // prefetch gi for t+1 (plain cached loads; overlaps the poll below)
            const int te2 = d ? (NT - 2 - t) : (t + 1);
#pragma unroll
            for (int r = 0; r < 4; r++) {
                const f16* p = giD + ((size_t)(bC + r) * NT + te2) * NH3;
#pragma unroll
                for (int g = 0; g < 3; g++) gif[g][r] = (float)p[g * 512 + cl];
            }
        }
        // y output (nontemporal: streaming, don't pollute L2)
#pragma unroll
        for (int r = 0; r < 4; r++) {
            const size_t yoff = ((size_t)(bC + r) * NT + te) * (2 * NH) + d * NH + cl;
            if (y16) __builtin_nontemporal_store(hnew16[r], &y16[yoff]);
            else     __builtin_nontemporal_store(hnew[r], &y32[yoff]);
        }
        if (t == NT - 1) {
#pragma unroll
            for (int r = 0; r < 4; r++)
                hlast[d * NB * NH + (bC + r) * NH + cl] = hnew[r];
        }
        if (more) {
            // per-wave poll: lanes 0..15 each watch 2 u32 flags (one u64 load).
            // Monotonic >= test — immune to leaders racing ahead.
            const unsigned target = (unsigned)(t + 1);
            bool done;
            do {
                unsigned lo = target, hi = target;
                if (lane < 16) {
                    const unsigned long long v = ld_dev_u64(FQ + lane);
                    lo = (unsigned)v;
                    hi = (unsigned)(v >> 32);
                }
                done = __all(lo >= target && hi >= target);
            } while (!done);
        }
    }
}

extern "C" void kernel_launch(void* const* d_in, const int* in_sizes, int n_in,
                              void* d_out, int out_size, void* d_ws, size_t ws_size,
                              hipStream_t stream) {
    (void)in_sizes; (void)n_in; (void)out_size; (void)ws_size;
    const float* X     = (const float*)d_in[0];
    const float* wih0f = (const float*)d_in[1];
    const float* bih0f = (const float*)d_in[2];
    const float* whh0f = (const float*)d_in[3];
    const float* bhh0f = (const float*)d_in[4];
    const float* wih0r = (const float*)d_in[5];
    const float* bih0r = (const float*)d_in[6];
    const float* whh0r = (const float*)d_in[7];
    const float* bhh0r = (const float*)d_in[8];
    const float* wih1f = (const float*)d_in[9];
    const float* bih1f = (const float*)d_in[10];
    const float* whh1f = (const float*)d_in[11];
    const float* bhh1f = (const float*)d_in[12];
    const float* wih1r = (const float*)d_in[13];
    const float* bih1r = (const float*)d_in[14];
    const float* whh1r = (const float*)d_in[15];
    const float* bhh1r = (const float*)d_in[16];

    char* ws = (char*)d_ws;
    f16* Xh   = (f16*)(ws + 0ull);
    f16* Wi0f = (f16*)(ws + 33554432ull);
    f16* Wi0r = (f16*)(ws + 35127296ull);
    f16* Wh0f = (f16*)(ws + 36700160ull);
    f16* Wh0r = (f16*)(ws + 38273024ull);
    f16* Wi1f = (f16*)(ws + 39845888ull);
    f16* Wi1r = (f16*)(ws + 42991616ull);
    f16* Wh1f = (f16*)(ws + 46137344ull);
    f16* Wh1r = (f16*)(ws + 47710208ull);
    f16* Y0h  = (f16*)(ws + 49283072ull);
    f16* H16  = (f16*)(ws + 116391936ull);
    unsigned* SYNC = (unsigned*)(ws + 116654080ull);
    f16* GI   = (f16*)(ws + 116655104ull);
    float* out = (float*)d_out;

    init_buf<<<512, 256, 0, stream>>>(H16, SYNC);

    auto cvt = [&](const float* s, f16* d, size_t n) {
        int n4 = (int)(n / 4);
        int grid = (n4 + 255) / 256; if (grid > 4096) grid = 4096;
        cvt_f16<<<grid, 256, 0, stream>>>(s, d, n4);
    };
    cvt(X,     Xh,   (size_t)NM * NH);
    cvt(wih0f, Wi0f, (size_t)NH3 * NH);
    cvt(wih0r, Wi0r, (size_t)NH3 * NH);
    cvt(whh0f, Wh0f, (size_t)NH3 * NH);
    cvt(whh0r, Wh0r, (size_t)NH3 * NH);
    cvt(wih1f, Wi1f, (size_t)NH3 * 2 * NH);
    cvt(wih1r, Wi1r, (size_t)NH3 * 2 * NH);
    cvt(whh1f, Wh1f, (size_t)NH3 * NH);
    cvt(whh1r, Wh1r, (size_t)NH3 * NH);

    const size_t OUT0 = (size_t)NM * 2 * NH;   // 33,554,432 floats

    // Layer 0 (flags: u32[2][32] at SYNC; layer 1 uses the next 64 u32)
    gemm_gi<<<dim3(NM / 128, 24), 256, 0, stream>>>(Xh, Wi0f, Wi0r, bih0f, bih0r, GI, NH);
    gru_scan<<<64, 128, 0, stream>>>(GI, Wh0f, Wh0r, bhh0f, bhh0r,
                                     H16, Y0h, nullptr,
                                     out + OUT0, SYNC);
    // Layer 1
    gemm_gi<<<dim3(NM / 128, 24), 256, 0, stream>>>(Y0h, Wi1f, Wi1r, bih1f, bih1r, GI, 2 * NH);
    gru_scan<<<64, 128, 0, stream>>>(GI, Wh1f, Wh1r, bhh1f, bhh1r,
                                     H16 + 2 * 2 * NB * NH, nullptr, out,
                                     out + OUT0 + 2 * NB * NH, SYNC + 64);
}

// Round 5
// 9018.995 us; speedup vs baseline: 2.6632x; 1.1496x over previous
//
#include <hip/hip_runtime.h>

typedef _Float16 f16;
typedef _Float16 half8 __attribute__((ext_vector_type(8)));
typedef _Float16 half4v __attribute__((ext_vector_type(4)));
typedef float float4v __attribute__((ext_vector_type(4)));

constexpr int NB = 32;            // batch
constexpr int NT = 1024;          // time
constexpr int NH = 512;           // hidden
constexpr int NH3 = 1536;
constexpr int NM = NB * NT;       // 32768 rows

// Tagged h-exchange buffer: HB[dir][buf][slice 32][batch 32][chunk 6] u64.
// Chunk = 3 f16 payload | 16-bit generation tag (bits 48..63). One aligned 8B
// store => tag+data atomic. Per layer: 24576 u64 = 192KB (re-zeroed between layers).
constexpr int HB_U64 = 2 * 2 * 32 * 32 * 6;   // 24576

// ---------------- init: zero tagged exchange buffer ----------------
__global__ void init_hb(unsigned long long* __restrict__ hb) {
    int i = blockIdx.x * 256 + threadIdx.x;
    if (i < HB_U64) hb[i] = 0ull;
}

// ---------------- fp32 -> fp16 convert ----------------
__global__ void cvt_f16(const float* __restrict__ src, f16* __restrict__ dst, int n4) {
    int i = blockIdx.x * blockDim.x + threadIdx.x;
    int stride = gridDim.x * blockDim.x;
    for (; i < n4; i += stride) {
        float4v v = *(const float4v*)(src + 4 * (size_t)i);
        half4v h;
        h[0] = (f16)v[0]; h[1] = (f16)v[1]; h[2] = (f16)v[2]; h[3] = (f16)v[3];
        *(half4v*)(dst + 4 * (size_t)i) = h;
    }
}

// ---------------- gi GEMM: gi[dir][m][n] = A[m][:] . W[n][:] + bias[n] ----------------
__global__ __launch_bounds__(256, 2) void gemm_gi(
    const f16* __restrict__ A, const f16* __restrict__ Wf, const f16* __restrict__ Wr,
    const float* __restrict__ bf, const float* __restrict__ br,
    f16* __restrict__ gi, int K)
{
    __shared__ f16 As[128 * 72];
    __shared__ f16 Bs[128 * 72];
    const int m0 = blockIdx.x * 128;
    const int n0g = blockIdx.y * 128;
    const int dir = (n0g >= NH3) ? 1 : 0;
    const f16* __restrict__ W = dir ? Wr : Wf;
    const float* __restrict__ bias = dir ? br : bf;
    const int n0 = n0g - dir * NH3;
    const int tid = threadIdx.x;
    const int lane = tid & 63;
    const int wv = tid >> 6;
    const int wm = wv & 1;
    const int wn = wv >> 1;
    const int srow = tid >> 3;          // 0..31
    const int scol = (tid & 7) * 8;     // halves

    float4v acc[4][4] = {};
    for (int kb = 0; kb < K; kb += 64) {
        int4 av[4], bv[4];
#pragma unroll
        for (int i = 0; i < 4; i++) {
            av[i] = *(const int4*)(A + (size_t)(m0 + srow + i * 32) * K + kb + scol);
            bv[i] = *(const int4*)(W + (size_t)(n0 + srow + i * 32) * K + kb + scol);
        }
        __syncthreads();
#pragma unroll
        for (int i = 0; i < 4; i++) {
            *(int4*)(As + (srow + i * 32) * 72 + scol) = av[i];
            *(int4*)(Bs + (srow + i * 32) * 72 + scol) = bv[i];
        }
        __syncthreads();
#pragma unroll
        for (int ks = 0; ks < 2; ks++) {
            half8 af[4], bw[4];
#pragma unroll
            for (int i = 0; i < 4; i++) {
                af[i] = *(const half8*)(As + (wm * 64 + i * 16 + (lane & 15)) * 72 + ks * 32 + (lane >> 4) * 8);
                bw[i] = *(const half8*)(Bs + (wn * 64 + i * 16 + (lane & 15)) * 72 + ks * 32 + (lane >> 4) * 8);
            }
#pragma unroll
            for (int i = 0; i < 4; i++)
#pragma unroll
                for (int j = 0; j < 4; j++)
                    acc[i][j] = __builtin_amdgcn_mfma_f32_16x16x32_f16(af[i], bw[j], acc[i][j], 0, 0, 0);
        }
    }
    f16* __restrict__ gid = gi + (size_t)dir * NM * NH3;
#pragma unroll
    for (int i = 0; i < 4; i++) {
        const int m = m0 + wm * 64 + i * 16 + ((lane >> 4) << 2);
#pragma unroll
        for (int j = 0; j < 4; j++) {
            const int n = n0 + wn * 64 + j * 16 + (lane & 15);
            const float b = bias[n];
#pragma unroll
            for (int r = 0; r < 4; r++)
                gid[(size_t)(m + r) * NH3 + n] = (f16)(acc[i][j][r] + b);
        }
    }
}

// ---------------- device-coherent helpers ----------------
__device__ __forceinline__ unsigned long long ld_dev_u64(const void* p) {
    return __hip_atomic_load((const unsigned long long*)p,
                             __ATOMIC_RELAXED, __HIP_MEMORY_SCOPE_AGENT);
}
__device__ __forceinline__ void st_dev_u64(void* p, unsigned long long v) {
    __hip_atomic_store((unsigned long long*)p, v,
                       __ATOMIC_RELAXED, __HIP_MEMORY_SCOPE_AGENT);
}

union U4H8 { unsigned u[4]; half8 h; };

// ---------------- GRU scan ----------------
// grid = 64 blocks: blockIdx/32 = dir, blockIdx%32 = 16-col slice. 128 threads (2 waves).
// h exchange is TAGGED PAYLOAD: each 8B chunk = 3 f16 + generation tag, stored with one
// atomic-relaxed agent store. Consumers poll the chunks they need until all tags == t.
// No store drain, no flags, no separate load phase: ~2 coherent RTs/step instead of ~4.5.
__global__ __launch_bounds__(128, 1) void gru_scan(
    const f16* __restrict__ gi,      // [2][NM][1536]
    const f16* __restrict__ Whf, const f16* __restrict__ Whr,   // [1536][512]
    const float* __restrict__ bhf, const float* __restrict__ bhr,
    unsigned long long* __restrict__ HB,   // [2][2][32][32][6] tagged chunks
    f16* __restrict__ y16,           // layer0 output (fp16) or nullptr
    float* __restrict__ y32,         // layer1 output (fp32, d_out) or nullptr
    float* __restrict__ hlast)       // [2][NB][NH] fp32
{
    __shared__ f16 Wlds[48 * 520];
    __shared__ unsigned short Tt[32][18];   // per-block transpose tile (pad 18)
    const int d = blockIdx.x >> 5;
    const int cs = blockIdx.x & 31;
    const int c0 = cs * 16;
    const f16* __restrict__ W = d ? Whr : Whf;
    const float* __restrict__ bhh = d ? bhr : bhf;
    const int tid = threadIdx.x;
    const int lane = tid & 63;
    const int mt = tid >> 6;         // wave index = batch half

    // stage W_hh rows {g*512 + c0 + j} into LDS (row-major [48][520], padded)
    for (int c = tid; c < 48 * 64; c += 128) {
        const int row = c >> 6;
        const int off = (c & 63) * 8;
        const int g = row >> 4, j = row & 15;
        *(int4*)(Wlds + row * 520 + off) = *(const int4*)(W + (size_t)(g * 512 + c0 + j) * 512 + off);
    }
    if (tid < 64) Tt[tid >> 1][16 + (tid & 1)] = 0;   // zero pad columns
    const int cl = c0 + (lane & 15);
    float bh[3];
#pragma unroll
    for (int g = 0; g < 3; g++) bh[g] = bhh[g * 512 + cl];
    __syncthreads();

    // hoist B fragments (step-invariant): 48 x half8
    half8 bfr[16][3];
#pragma unroll
    for (int kk = 0; kk < 16; kk++)
#pragma unroll
        for (int g = 0; g < 3; g++)
            bfr[kk][g] = *(const half8*)(Wlds + (g * 16 + (lane & 15)) * 520 + kk * 32 + (lane >> 4) * 8);

    const f16* __restrict__ giD = gi + (size_t)d * NM * NH3;
    const int bA = mt * 16 + (lane & 15);          // A-frag row (batch)
    const int bC = mt * 16 + ((lane >> 4) << 2);   // C-frag batch base (+r)
    const int g0 = (lane >> 4) & 1;                // which 8-half group
    const int csBase = (lane >> 4) >> 1;           // slice parity
    // lane-constant chunk offset within a dir-buf region:
    const int chunkBase = (csBase * 32 + bA) * 6 + g0 * 3;

    float h32[4] = {0.f, 0.f, 0.f, 0.f};
    float gif[3][4];
    {
        const int te = d ? (NT - 1) : 0;
#pragma unroll
        for (int r = 0; r < 4; r++) {
            const f16* p = giD + ((size_t)(bC + r) * NT + te) * NH3;
#pragma unroll
            for (int g = 0; g < 3; g++) gif[g][r] = (float)p[g * 512 + cl];
        }
    }

    for (int t = 0; t < NT; t++) {
        const int te = d ? (NT - 1 - t) : t;
        const unsigned long long* const HBr = HB + (size_t)(d * 2 + (t & 1)) * 6144;
        const unsigned tagT = (unsigned)t;

        // -------- poll + load: all 48 tagged chunks until every tag == t --------
        unsigned long long ch[16][3];
        bool ok;
        do {
#pragma unroll
            for (int kk = 0; kk < 16; kk++) {
                const unsigned long long* p = HBr + chunkBase + kk * 384;
                ch[kk][0] = ld_dev_u64(p);
                ch[kk][1] = ld_dev_u64(p + 1);
                ch[kk][2] = ld_dev_u64(p + 2);
            }
            unsigned bad = 0;
#pragma unroll
            for (int kk = 0; kk < 16; kk++)
#pragma unroll
                for (int ci = 0; ci < 3; ci++)
                    bad |= (unsigned)(ch[kk][ci] >> 48) ^ tagT;
            ok = __all(bad == 0);
        } while (!ok);

        // -------- extract fragments + MFMA --------
        float4v acc[3] = {};
#pragma unroll
        for (int kk = 0; kk < 16; kk++) {
            const unsigned A_lo = (unsigned)ch[kk][0], A_hi = (unsigned)(ch[kk][0] >> 32);
            const unsigned B_lo = (unsigned)ch[kk][1], B_hi = (unsigned)(ch[kk][1] >> 32);
            const unsigned C_lo = (unsigned)ch[kk][2];
            U4H8 u;
            u.u[0] = A_lo;
            u.u[1] = (A_hi & 0xffffu) | (B_lo << 16);
            u.u[2] = (B_lo >> 16) | (B_hi << 16);
            u.u[3] = C_lo;
#pragma unroll
            for (int g = 0; g < 3; g++)
                acc[g] = __builtin_amdgcn_mfma_f32_16x16x32_f16(u.h, bfr[kk][g], acc[g], 0, 0, 0);
        }

        float hnew[4]; f16 hnew16[4];
#pragma unroll
        for (int r = 0; r < 4; r++) {
            const float hr = acc[0][r] + bh[0];
            const float hz = acc[1][r] + bh[1];
            const float hn = acc[2][r] + bh[2];
            const float rg = 1.f / (1.f + __expf(-(gif[0][r] + hr)));
            const float zg = 1.f / (1.f + __expf(-(gif[1][r] + hz)));
            const float x2 = gif[2][r] + rg * hn;
            const float e2 = __expf(x2 + x2);
            const float ng = 1.f - 2.f / (e2 + 1.f);
            const float h = (1.f - zg) * ng + zg * h32[r];
            h32[r] = h; hnew[r] = h; hnew16[r] = (f16)h;
        }

        const bool more = (t + 1 < NT);
        if (more) {
            // -------- publish h_{t+1}: LDS transpose -> 192 contiguous tagged u64 --------
#pragma unroll
            for (int r = 0; r < 4; r++)
                Tt[bC + r][lane & 15] = __builtin_bit_cast(unsigned short, hnew16[r]);
            __syncthreads();
            {
                const unsigned long long tagw = ((unsigned long long)(unsigned)(t + 1)) << 48;
                unsigned long long* const HBw =
                    HB + (size_t)(d * 2 + ((t + 1) & 1)) * 6144 + (size_t)cs * 192;
#pragma unroll
                for (int s = 0; s < 2; s++) {
                    const int cf = tid + s * 128;
                    if (cf < 192) {
                        const int b = cf / 6, c = cf % 6;
                        const int j0 = (c / 3) * 8 + (c % 3) * 3;
                        const unsigned long long h0 = Tt[b][j0];
                        const unsigned long long h1 = Tt[b][j0 + 1];
                        const unsigned long long h2 = Tt[b][j0 + 2];
                        st_dev_u64(HBw + cf, h0 | (h1 << 16) | (h2 << 32) | tagw);
                    }
                }
            }
            __syncthreads();   // protect Tt reads from next iteration's writes
        }
        // -------- y output (nontemporal streaming) --------
#pragma unroll
        for (int r = 0; r < 4; r++) {
            const size_t yoff = ((size_t)(bC + r) * NT + te) * (2 * NH) + d * NH + cl;
            if (y16) __builtin_nontemporal_store(hnew16[r], &y16[yoff]);
            else     __builtin_nontemporal_store(hnew[r], &y32[yoff]);
        }
        if (t == NT - 1) {
#pragma unroll
            for (int r = 0; r < 4; r++)
                hlast[d * NB * NH + (bC + r) * NH + cl] = hnew[r];
        }
        if (more) {
            // prefetch gi for t+1 (plain cached; in flight during next poll)
            const int te2 = d ? (NT - 2 - t) : (t + 1);
#pragma unroll
            for (int r = 0; r < 4; r++) {
                const f16* p = giD + ((size_t)(bC + r) * NT + te2) * NH3;
#pragma unroll
                for (int g = 0; g < 3; g++) gif[g][r] = (float)p[g * 512 + cl];
            }
        }
    }
}

extern "C" void kernel_launch(void* const* d_in, const int* in_sizes, int n_in,
                              void* d_out, int out_size, void* d_ws, size_t ws_size,
                              hipStream_t stream) {
    (void)in_sizes; (void)n_in; (void)out_size; (void)ws_size;
    const float* X     = (const float*)d_in[0];
    const float* wih0f = (const float*)d_in[1];
    const float* bih0f = (const float*)d_in[2];
    const float* whh0f = (const float*)d_in[3];
    const float* bhh0f = (const float*)d_in[4];
    const float* wih0r = (const float*)d_in[5];
    const float* bih0r = (const float*)d_in[6];
    const float* whh0r = (const float*)d_in[7];
    const float* bhh0r = (const float*)d_in[8];
    const float* wih1f = (const float*)d_in[9];
    const float* bih1f = (const float*)d_in[10];
    const float* whh1f = (const float*)d_in[11];
    const float* bhh1f = (const float*)d_in[12];
    const float* wih1r = (const float*)d_in[13];
    const float* bih1r = (const float*)d_in[14];
    const float* whh1r = (const float*)d_in[15];
    const float* bhh1r = (const float*)d_in[16];

    char* ws = (char*)d_ws;
    f16* Xh   = (f16*)(ws + 0ull);
    f16* Wi0f = (f16*)(ws + 33554432ull);
    f16* Wi0r = (f16*)(ws + 35127296ull);
    f16* Wh0f = (f16*)(ws + 36700160ull);
    f16* Wh0r = (f16*)(ws + 38273024ull);
    f16* Wi1f = (f16*)(ws + 39845888ull);
    f16* Wi1r = (f16*)(ws + 42991616ull);
    f16* Wh1f = (f16*)(ws + 46137344ull);
    f16* Wh1r = (f16*)(ws + 47710208ull);
    f16* Y0h  = (f16*)(ws + 49283072ull);
    unsigned long long* HBu = (unsigned long long*)(ws + 116391936ull);  // 192KB, shared by both layers
    f16* GI   = (f16*)(ws + 116655104ull);
    float* out = (float*)d_out;

    auto cvt = [&](const float* s, f16* d, size_t n) {
        int n4 = (int)(n / 4);
        int grid = (n4 + 255) / 256; if (grid > 4096) grid = 4096;
        cvt_f16<<<grid, 256, 0, stream>>>(s, d, n4);
    };
    cvt(X,     Xh,   (size_t)NM * NH);
    cvt(wih0f, Wi0f, (size_t)NH3 * NH);
    cvt(wih0r, Wi0r, (size_t)NH3 * NH);
    cvt(whh0f, Wh0f, (size_t)NH3 * NH);
    cvt(whh0r, Wh0r, (size_t)NH3 * NH);
    cvt(wih1f, Wi1f, (size_t)NH3 * 2 * NH);
    cvt(wih1r, Wi1r, (size_t)NH3 * 2 * NH);
    cvt(whh1f, Wh1f, (size_t)NH3 * NH);
    cvt(whh1r, Wh1r, (size_t)NH3 * NH);

    const size_t OUT0 = (size_t)NM * 2 * NH;   // 33,554,432 floats

    // Layer 0
    init_hb<<<96, 256, 0, stream>>>(HBu);
    gemm_gi<<<dim3(NM / 128, 24), 256, 0, stream>>>(Xh, Wi0f, Wi0r, bih0f, bih0r, GI, NH);
    gru_scan<<<64, 128, 0, stream>>>(GI, Wh0f, Wh0r, bhh0f, bhh0r,
                                     HBu, Y0h, nullptr, out + OUT0);
    // Layer 1 (reset tags, reuse HB)
    init_hb<<<96, 256, 0, stream>>>(HBu);
    gemm_gi<<<dim3(NM / 128, 24), 256, 0, stream>>>(Y0h, Wi1f, Wi1r, bih1f, bih1r, GI, 2 * NH);
    gru_scan<<<64, 128, 0, stream>>>(GI, Wh1f, Wh1r, bhh1f, bhh1r,
                                     HBu, nullptr, out, out + OUT0 + 2 * NB * NH);
}